// Round 1
// baseline (2234.499 us; speedup 1.0000x reference)
//
#include <hip/hip_runtime.h>
#include <cmath>

// ---------------------------------------------------------------------------
// MoEProjector: router(softmax,top2) -> per-expert [Linear -> GELU -> Linear]
// -> gate-weighted combine -> *gate_scale -> LayerNorm.
// T=8192 tokens, D=1024, O=4096, E=4, top-2.
// R3: GEMM core upgraded m97(128^2, 2-barrier) -> 256^2 8-phase schedule
//     (T2 LDS XOR-swizzle + T3/T4 counted vmcnt + T5 setprio + T1 XCD swizzle).
// ---------------------------------------------------------------------------

typedef float f32x4 __attribute__((ext_vector_type(4)));
typedef __bf16 bf16x8 __attribute__((ext_vector_type(8)));
typedef __bf16 bf16x4 __attribute__((ext_vector_type(4)));

#define T_TOK 8192
#define DDIM 1024
#define ODIM 4096
#define NEXP 4

__device__ __forceinline__ void gl_lds16(const void* g, void* l) {
    __builtin_amdgcn_global_load_lds(
        (const __attribute__((address_space(1))) void*)g,
        (__attribute__((address_space(3))) void*)l, 16, 0, 0);
}

// ---------------- x fp32 -> bf16 (vectorized) ----------------
__global__ __launch_bounds__(256) void cvt_bf16_vec(const float* __restrict__ in,
                                                    __bf16* __restrict__ out, int n4) {
    int i = blockIdx.x * 256 + threadIdx.x;
    if (i >= n4) return;
    float4 v = ((const float4*)in)[i];
    bf16x4 o = { (__bf16)v.x, (__bf16)v.y, (__bf16)v.z, (__bf16)v.w };
    ((bf16x4*)out)[i] = o;
}

// ------------- W [R,C] fp32 -> Wt [C,R] bf16, per expert (z) -------------
__global__ __launch_bounds__(256) void transpose_cvt(const float* __restrict__ in,
                                                     __bf16* __restrict__ out,
                                                     int R, int C) {
    __shared__ float tile[32][33];
    const size_t eoff = (size_t)blockIdx.z * R * C;
    const float* ip = in + eoff;
    __bf16* op = out + eoff;
    const int c0 = blockIdx.x * 32, r0 = blockIdx.y * 32;
    const int tx = threadIdx.x, ty = threadIdx.y;  // 32 x 8
#pragma unroll
    for (int i = 0; i < 4; i++)
        tile[ty + i * 8][tx] = ip[(size_t)(r0 + ty + i * 8) * C + c0 + tx];
    __syncthreads();
#pragma unroll
    for (int i = 0; i < 4; i++)
        op[(size_t)(c0 + ty + i * 8) * R + r0 + tx] = (__bf16)tile[tx][ty + i * 8];
}

// -------- router: fp32 logits -> softmax -> top2 -> compacted lists --------
__global__ __launch_bounds__(256) void router_kernel(const float* __restrict__ x,
                                                     const float* __restrict__ Wg,
                                                     const float* __restrict__ bg,
                                                     int* __restrict__ counts,
                                                     int* __restrict__ perm,
                                                     float* __restrict__ wlist) {
    const int wave = threadIdx.x >> 6, lane = threadIdx.x & 63;
    const int t = blockIdx.x * 4 + wave;
    const float* xr = x + (size_t)t * DDIM;
    float a0 = 0.f, a1 = 0.f, a2 = 0.f, a3 = 0.f;
    const float4* Wg4 = (const float4*)Wg;  // Wg[d*4 + e] contiguous over e
    for (int d = lane; d < DDIM; d += 64) {
        float xv = xr[d];
        float4 w = Wg4[d];
        a0 += xv * w.x; a1 += xv * w.y; a2 += xv * w.z; a3 += xv * w.w;
    }
#pragma unroll
    for (int off = 32; off; off >>= 1) {
        a0 += __shfl_xor(a0, off); a1 += __shfl_xor(a1, off);
        a2 += __shfl_xor(a2, off); a3 += __shfl_xor(a3, off);
    }
    if (lane == 0) {
        float l[4] = {a0 + bg[0], a1 + bg[1], a2 + bg[2], a3 + bg[3]};
        float mx = fmaxf(fmaxf(l[0], l[1]), fmaxf(l[2], l[3]));
        float p[4], s = 0.f;
#pragma unroll
        for (int e = 0; e < 4; e++) { p[e] = expf(l[e] - mx); s += p[e]; }
#pragma unroll
        for (int e = 0; e < 4; e++) p[e] /= s;
        int e1 = 0;  // argmax, lowest index on ties (strict >)
#pragma unroll
        for (int e = 1; e < 4; e++) if (p[e] > p[e1]) e1 = e;
        int e2 = (e1 == 0) ? 1 : 0;
#pragma unroll
        for (int e = 0; e < 4; e++) if (e != e1 && p[e] > p[e2]) e2 = e;
        const float inv = 1.0f / (p[e1] + p[e2]);
        int pos1 = atomicAdd(&counts[e1], 1);
        perm[e1 * T_TOK + pos1] = t;
        wlist[e1 * T_TOK + pos1] = p[e1] * inv;
        int pos2 = atomicAdd(&counts[e2], 1);
        perm[e2 * T_TOK + pos2] = t;
        wlist[e2 * T_TOK + pos2] = p[e2] * inv;
    }
}

// ===========================================================================
// 256x256 8-phase GEMM:  C[M,N] = A[M,K] @ B^T[N,K]  (bf16 in, fp32 acc)
// MODE 0: A rows gathered via perm (tokens);  H[i] = gelu(acc + b1) -> bf16
// MODE 1: A = H dense rows;  out[perm[i]] += wlist[i] * (acc + b2) (fp32 RMW)
//
// Schedule (per K-tile t, buf b=t&1; phases p=0..3):
//   p0: ds_read 8 B-frags + A-frags{0,1}; STAGE Ah0(t+1)->buf b^1
//   p1: ds_read A-frags{2,3};             STAGE Ah1(t+1)->buf b^1
//   p2: ds_read A-frags{4,5};             STAGE Bh0(t+2)->buf b
//   p3: ds_read A-frags{6,7};             STAGE Bh1(t+2)->buf b
//       + s_waitcnt vmcnt(4)  (counted: leaves Bh(t+2) in flight)
//   each phase: barrier; lgkmcnt(0); setprio(1); 16 MFMA; setprio(0); barrier
// Safety invariants:
//   - A(t+1) overwrites A(t-1): last read at tile t-1 p3, >=2 barriers before.
//   - B(t+2) overwrites B(t): B only read at tile t p0, >=2 barriers before.
//   - vmcnt(4) at end of tile t => A(t+1),B(t+1) fully landed before tile t+1.
// LDS swizzle (T2): row stride 128B; 16B-chunk index q stored at q^(row&7).
// global_load_lds writes linearly, so the GLOBAL source is pre-swizzled and
// the same XOR is applied on ds_read (involution).
// ===========================================================================

#define STAGE_A(t, h, bb)                                                      \
  if ((t) < NT) {                                                              \
    gl_lds16(pa##h##0 + (size_t)(t) * BK, &As[bb][h][w * 512]);                \
    gl_lds16(pa##h##1 + (size_t)(t) * BK, &As[bb][h][w * 512 + 4096]);         \
  }
#define STAGE_B(t, h, bb)                                                      \
  if ((t) < NT) {                                                              \
    gl_lds16(pb##h##0 + (size_t)(t) * BK, &Bs[bb][h][w * 512]);                \
    gl_lds16(pb##h##1 + (size_t)(t) * BK, &Bs[bb][h][w * 512 + 4096]);         \
  }
#define LDA(bb, mg, kk) (*(const bf16x8*)&As[bb][wr][(mg)*1024 + rowOff + offK##kk])
#define LDB(bb, nn, kk) (*(const bf16x8*)&Bs[bb][wch][(nn)*1024 + rowBOff + offK##kk])
#define MFMA4(p, nn)                                                           \
  acc[2*(p)][nn]   = __builtin_amdgcn_mfma_f32_16x16x32_bf16(af0k0, bfr[nn][0], acc[2*(p)][nn], 0, 0, 0);   \
  acc[2*(p)][nn]   = __builtin_amdgcn_mfma_f32_16x16x32_bf16(af0k1, bfr[nn][1], acc[2*(p)][nn], 0, 0, 0);   \
  acc[2*(p)+1][nn] = __builtin_amdgcn_mfma_f32_16x16x32_bf16(af1k0, bfr[nn][0], acc[2*(p)+1][nn], 0, 0, 0); \
  acc[2*(p)+1][nn] = __builtin_amdgcn_mfma_f32_16x16x32_bf16(af1k1, bfr[nn][1], acc[2*(p)+1][nn], 0, 0, 0);
#define PHASE_TAIL(p)                                                          \
  __builtin_amdgcn_s_barrier();                                                \
  asm volatile("s_waitcnt lgkmcnt(0)" ::: "memory");                           \
  __builtin_amdgcn_s_setprio(1);                                               \
  MFMA4(p, 0) MFMA4(p, 1) MFMA4(p, 2) MFMA4(p, 3)                              \
  __builtin_amdgcn_s_setprio(0);                                               \
  __builtin_amdgcn_s_barrier();
#define TILE(bb, t)                                                            \
  {                                                                            \
    bfr[0][0] = LDB(bb, 0, 0); bfr[0][1] = LDB(bb, 0, 1);                      \
    bfr[1][0] = LDB(bb, 1, 0); bfr[1][1] = LDB(bb, 1, 1);                      \
    bfr[2][0] = LDB(bb, 2, 0); bfr[2][1] = LDB(bb, 2, 1);                      \
    bfr[3][0] = LDB(bb, 3, 0); bfr[3][1] = LDB(bb, 3, 1);                      \
    af0k0 = LDA(bb, 0, 0); af0k1 = LDA(bb, 0, 1);                              \
    af1k0 = LDA(bb, 1, 0); af1k1 = LDA(bb, 1, 1);                              \
    STAGE_A((t) + 1, 0, (bb) ^ 1)                                              \
    PHASE_TAIL(0)                                                              \
    af0k0 = LDA(bb, 2, 0); af0k1 = LDA(bb, 2, 1);                              \
    af1k0 = LDA(bb, 3, 0); af1k1 = LDA(bb, 3, 1);                              \
    STAGE_A((t) + 1, 1, (bb) ^ 1)                                              \
    PHASE_TAIL(1)                                                              \
    af0k0 = LDA(bb, 4, 0); af0k1 = LDA(bb, 4, 1);                              \
    af1k0 = LDA(bb, 5, 0); af1k1 = LDA(bb, 5, 1);                              \
    STAGE_B((t) + 2, 0, bb)                                                    \
    PHASE_TAIL(2)                                                              \
    af0k0 = LDA(bb, 6, 0); af0k1 = LDA(bb, 6, 1);                              \
    af1k0 = LDA(bb, 7, 0); af1k1 = LDA(bb, 7, 1);                              \
    STAGE_B((t) + 2, 1, bb)                                                    \
    if ((t) + 2 < NT) { asm volatile("s_waitcnt vmcnt(4)" ::: "memory"); }     \
    else              { asm volatile("s_waitcnt vmcnt(0)" ::: "memory"); }     \
    PHASE_TAIL(3)                                                              \
  }

template <int MODE, int KDIM>
__global__ __launch_bounds__(512, 2) void moe_gemm256(
    const __bf16* __restrict__ A, const __bf16* __restrict__ B,
    const float* __restrict__ bias, __bf16* __restrict__ Hout,
    float* __restrict__ Fout, const int* __restrict__ perm,
    const float* __restrict__ wlist, const int* __restrict__ countp) {
    constexpr int BK = 64;
    constexpr int NT = KDIM / BK;
    constexpr int GX = ODIM / 256;  // 16 N-blocks

    __shared__ __align__(16) __bf16 As[2][2][128 * 64];  // [buf][half][row*64+col]
    __shared__ __align__(16) __bf16 Bs[2][2][128 * 64];

    const int count = *countp;
    const int nAy = (count + 255) >> 8;  // active M-blocks
    const int na = nAy * GX;             // active blocks
    int lin = blockIdx.y * GX + blockIdx.x;
    if (lin >= na) return;               // block-uniform early exit
    {   // T1: bijective XCD swizzle over the ACTIVE range [0,na) (m204 form)
        const int q = na >> 3, r = na & 7;
        const int xcd = lin & 7, loc = lin >> 3;
        lin = xcd * q + (xcd < r ? xcd : r) + loc;
    }
    const int bx = lin & (GX - 1), by = lin / GX;
    const int m0 = by * 256, n0 = bx * 256;

    const int tid = threadIdx.x;
    const int w = tid >> 6, lane = tid & 63;
    const int r16 = lane & 15, quad = lane >> 4;
    const int wr = w >> 2;   // 0..1 : M half (128 rows)
    const int wc = w & 3;    // 0..3 : N quarter (64 cols)
    const int wch = wc >> 1; // B half

    // per-lane swizzled LDS read offsets (bf16 elems); row&7 == r16&7 here
    const int swz = r16 & 7;
    const int offK0 = ((quad) ^ swz) * 8;
    const int offK1 = ((quad + 4) ^ swz) * 8;
    const int rowOff = r16 * 64;
    const int rowBOff = (wc & 1) * 4096 + rowOff;

    // staging: thread covers chunk c=tid of each half-tile (row srow, chunk q)
    // pre-swizzled GLOBAL source so linear gl_lds dest yields swizzled LDS
    const int srow = tid >> 3;                    // 0..63
    const int sq = ((tid & 7) ^ (srow & 7)) * 8;  // source col, elems
    const __bf16 *pa00, *pa01, *pa10, *pa11;
    if (MODE == 0) {  // gather token rows (padding rows -> token 0, perm zeroed)
        pa00 = A + (size_t)perm[m0 + srow] * KDIM + sq;
        pa01 = A + (size_t)perm[m0 + 64 + srow] * KDIM + sq;
        pa10 = A + (size_t)perm[m0 + 128 + srow] * KDIM + sq;
        pa11 = A + (size_t)perm[m0 + 192 + srow] * KDIM + sq;
    } else {
        pa00 = A + (size_t)(m0 + srow) * KDIM + sq;
        pa01 = A + (size_t)(m0 + 64 + srow) * KDIM + sq;
        pa10 = A + (size_t)(m0 + 128 + srow) * KDIM + sq;
        pa11 = A + (size_t)(m0 + 192 + srow) * KDIM + sq;
    }
    const __bf16* pb00 = B + (size_t)(n0 + srow) * KDIM + sq;
    const __bf16* pb01 = B + (size_t)(n0 + 64 + srow) * KDIM + sq;
    const __bf16* pb10 = B + (size_t)(n0 + 128 + srow) * KDIM + sq;
    const __bf16* pb11 = B + (size_t)(n0 + 192 + srow) * KDIM + sq;

    f32x4 acc[8][4] = {};
    bf16x8 bfr[4][2];
    bf16x8 af0k0, af0k1, af1k0, af1k1;

    // prologue: B(0), A(0), B(1); counted wait leaves B(1) in flight
    STAGE_B(0, 0, 0) STAGE_B(0, 1, 0)
    STAGE_A(0, 0, 0) STAGE_A(0, 1, 0)
    STAGE_B(1, 0, 1) STAGE_B(1, 1, 1)
    asm volatile("s_waitcnt vmcnt(4)" ::: "memory");
    __builtin_amdgcn_s_barrier();

    for (int t = 0; t < NT; t += 2) {
        TILE(0, t)
        TILE(1, t + 1)
    }

    // Epilogue. D frag layout: row = quad*4 + reg, col = lane&15.
    const int colBase = n0 + wc * 64 + r16;
    const int rowW = m0 + wr * 128 + quad * 4;
    if (MODE == 0) {
#pragma unroll
        for (int mg = 0; mg < 8; mg++) {
            const int rowBase = rowW + mg * 16;
#pragma unroll
            for (int n = 0; n < 4; n++) {
                const int col = colBase + n * 16;
                const float bv = bias[col];
#pragma unroll
                for (int r = 0; r < 4; r++) {
                    if (rowBase + r < count) {
                        float xv = acc[mg][n][r] + bv;
                        // tanh-form GELU: x * sigmoid(1.59577*x*(1+0.044715*x^2))
                        float u = 1.5957691216057308f * xv * (1.0f + 0.044715f * xv * xv);
                        float gv = xv * __builtin_amdgcn_rcpf(1.0f + __expf(-u));
                        Hout[(size_t)(rowBase + r) * ODIM + col] = (__bf16)gv;
                    }
                }
            }
        }
    } else {
#pragma unroll
        for (int mg = 0; mg < 8; mg++) {
            const int rowBase = rowW + mg * 16;
            int tok[4]; float g[4]; bool ok[4];
#pragma unroll
            for (int r = 0; r < 4; r++) {
                const int i = rowBase + r;
                ok[r] = (i < count);
                tok[r] = ok[r] ? perm[i] : 0;
                g[r] = ok[r] ? wlist[i] : 0.f;
            }
#pragma unroll
            for (int n = 0; n < 4; n++) {
                const int col = colBase + n * 16;
                const float bv = bias[col];
#pragma unroll
                for (int r = 0; r < 4; r++) {
                    if (ok[r]) {
                        float v = g[r] * (acc[mg][n][r] + bv);
                        Fout[(size_t)tok[r] * ODIM + col] += v;
                    }
                }
            }
        }
    }
}

#undef STAGE_A
#undef STAGE_B
#undef LDA
#undef LDB
#undef MFMA4
#undef PHASE_TAIL
#undef TILE

// ---------------- in-place LayerNorm over last dim (4096) ----------------
__global__ __launch_bounds__(256) void ln_kernel(float* __restrict__ out,
                                                 const float* __restrict__ lw,
                                                 const float* __restrict__ lb,
                                                 const float* __restrict__ gsp) {
    const int t = blockIdx.x;
    float* row = out + (size_t)t * ODIM;
    const float gs = gsp[0];
    float4 v[4];
    float s = 0.f, ss = 0.f;
#pragma unroll
    for (int i = 0; i < 4; i++) {
        float4 a = ((const float4*)row)[threadIdx.x + i * 256];
        a.x *= gs; a.y *= gs; a.z *= gs; a.w *= gs;
        v[i] = a;
        s += a.x + a.y + a.z + a.w;
        ss += a.x * a.x + a.y * a.y + a.z * a.z + a.w * a.w;
    }
#pragma unroll
    for (int off = 32; off; off >>= 1) {
        s += __shfl_xor(s, off);
        ss += __shfl_xor(ss, off);
    }
    __shared__ float rs[4], rss[4];
    const int wave = threadIdx.x >> 6, lane = threadIdx.x & 63;
    if (lane == 0) { rs[wave] = s; rss[wave] = ss; }
    __syncthreads();
    s = rs[0] + rs[1] + rs[2] + rs[3];
    ss = rss[0] + rss[1] + rss[2] + rss[3];
    const float mu = s * (1.0f / ODIM);
    const float var = ss * (1.0f / ODIM) - mu * mu;
    const float inv = 1.0f / sqrtf(var + 1e-5f);
#pragma unroll
    for (int i = 0; i < 4; i++) {
        const int c4 = threadIdx.x + i * 256;
        float4 w4 = ((const float4*)lw)[c4];
        float4 b4 = ((const float4*)lb)[c4];
        float4 o;
        o.x = (v[i].x - mu) * inv * w4.x + b4.x;
        o.y = (v[i].y - mu) * inv * w4.y + b4.y;
        o.z = (v[i].z - mu) * inv * w4.z + b4.z;
        o.w = (v[i].w - mu) * inv * w4.w + b4.w;
        ((float4*)row)[c4] = o;
    }
}

extern "C" void kernel_launch(void* const* d_in, const int* in_sizes, int n_in,
                              void* d_out, int out_size, void* d_ws, size_t ws_size,
                              hipStream_t stream) {
    const float* x   = (const float*)d_in[0];
    const float* Wg  = (const float*)d_in[1];
    const float* bg  = (const float*)d_in[2];
    const float* W1  = (const float*)d_in[3];
    const float* b1  = (const float*)d_in[4];
    const float* W2  = (const float*)d_in[5];
    const float* b2  = (const float*)d_in[6];
    const float* lnw = (const float*)d_in[7];
    const float* lnb = (const float*)d_in[8];
    const float* gsc = (const float*)d_in[9];
    float* out = (float*)d_out;

    // Workspace layout (~240 MB)
    char* w = (char*)d_ws;
    __bf16* Xb  = (__bf16*)w;                          // T*D bf16      = 16 MB
    __bf16* W1T = Xb + (size_t)T_TOK * DDIM;           // E*O*D bf16    = 32 MB
    __bf16* W2T = W1T + (size_t)NEXP * ODIM * DDIM;    // E*O*O bf16    = 128 MB
    __bf16* H   = W2T + (size_t)NEXP * ODIM * ODIM;    // T*O bf16      = 64 MB (per-expert reuse)
    int*   counts = (int*)(H + (size_t)T_TOK * ODIM);  // E ints
    int*   perm   = counts + NEXP;                     // E*T ints
    float* wlist  = (float*)(perm + NEXP * T_TOK);     // E*T floats

    // Zero routing lists (perm padding -> token 0) and the output accumulator.
    hipMemsetAsync(counts, 0, (NEXP + 2 * NEXP * T_TOK) * sizeof(int) , stream);
    hipMemsetAsync(out, 0, (size_t)T_TOK * ODIM * sizeof(float), stream);

    cvt_bf16_vec<<<(T_TOK * DDIM / 4) / 256, 256, 0, stream>>>(x, Xb, T_TOK * DDIM / 4);
    dim3 tb(32, 8);
    transpose_cvt<<<dim3(ODIM / 32, DDIM / 32, NEXP), tb, 0, stream>>>(W1, W1T, DDIM, ODIM);
    transpose_cvt<<<dim3(ODIM / 32, ODIM / 32, NEXP), tb, 0, stream>>>(W2, W2T, ODIM, ODIM);
    router_kernel<<<T_TOK / 4, 256, 0, stream>>>(x, Wg, bg, counts, perm, wlist);

    for (int e = 0; e < NEXP; e++) {
        moe_gemm256<0, DDIM><<<dim3(ODIM / 256, T_TOK / 256), 512, 0, stream>>>(
            Xb, W1T + (size_t)e * ODIM * DDIM, b1 + e * ODIM,
            H, nullptr, perm + e * T_TOK, nullptr, counts + e);
        moe_gemm256<1, ODIM><<<dim3(ODIM / 256, T_TOK / 256), 512, 0, stream>>>(
            H, W2T + (size_t)e * ODIM * ODIM, b2 + e * ODIM,
            nullptr, out, perm + e * T_TOK, wlist + e * T_TOK, counts + e);
    }
    ln_kernel<<<T_TOK, 256, 0, stream>>>(out, lnw, lnb, gsc);
}

// Round 2
// 1909.688 us; speedup vs baseline: 1.1701x; 1.1701x over previous
//
#include <hip/hip_runtime.h>
#include <cmath>

// ---------------------------------------------------------------------------
// MoEProjector: router(softmax,top2) -> per-expert [Linear -> GELU -> Linear]
// -> gate-weighted combine -> *gate_scale -> LayerNorm.
// T=8192 tokens, D=1024, O=4096, E=4, top-2.
// R4: staging-concurrency fixes on the 8-phase 256^2 core:
//   (1) expert-merged MODE0/MODE1 dispatches (kills 1-block/CU tail rounds),
//   (2) XCD->bx-pair mapping so B panels stay in the XCD's 4MB L2,
//   (3) vmcnt(4) moved after phase-3 MFMA (+1 phase of load slack),
//   (4) MODE1 epilogue via atomicAdd (race-free across merged experts).
// ---------------------------------------------------------------------------

typedef float f32x4 __attribute__((ext_vector_type(4)));
typedef __bf16 bf16x8 __attribute__((ext_vector_type(8)));
typedef __bf16 bf16x4 __attribute__((ext_vector_type(4)));

#define T_TOK 8192
#define DDIM 1024
#define ODIM 4096
#define NEXP 4

__device__ __forceinline__ void gl_lds16(const void* g, void* l) {
    __builtin_amdgcn_global_load_lds(
        (const __attribute__((address_space(1))) void*)g,
        (__attribute__((address_space(3))) void*)l, 16, 0, 0);
}

// ---------------- x fp32 -> bf16 (vectorized) ----------------
__global__ __launch_bounds__(256) void cvt_bf16_vec(const float* __restrict__ in,
                                                    __bf16* __restrict__ out, int n4) {
    int i = blockIdx.x * 256 + threadIdx.x;
    if (i >= n4) return;
    float4 v = ((const float4*)in)[i];
    bf16x4 o = { (__bf16)v.x, (__bf16)v.y, (__bf16)v.z, (__bf16)v.w };
    ((bf16x4*)out)[i] = o;
}

// ------------- W [R,C] fp32 -> Wt [C,R] bf16, per expert (z) -------------
__global__ __launch_bounds__(256) void transpose_cvt(const float* __restrict__ in,
                                                     __bf16* __restrict__ out,
                                                     int R, int C) {
    __shared__ float tile[32][33];
    const size_t eoff = (size_t)blockIdx.z * R * C;
    const float* ip = in + eoff;
    __bf16* op = out + eoff;
    const int c0 = blockIdx.x * 32, r0 = blockIdx.y * 32;
    const int tx = threadIdx.x, ty = threadIdx.y;  // 32 x 8
#pragma unroll
    for (int i = 0; i < 4; i++)
        tile[ty + i * 8][tx] = ip[(size_t)(r0 + ty + i * 8) * C + c0 + tx];
    __syncthreads();
#pragma unroll
    for (int i = 0; i < 4; i++)
        op[(size_t)(c0 + ty + i * 8) * R + r0 + tx] = (__bf16)tile[tx][ty + i * 8];
}

// -------- router: fp32 logits -> softmax -> top2 -> compacted lists --------
__global__ __launch_bounds__(256) void router_kernel(const float* __restrict__ x,
                                                     const float* __restrict__ Wg,
                                                     const float* __restrict__ bg,
                                                     int* __restrict__ counts,
                                                     int* __restrict__ perm,
                                                     float* __restrict__ wlist) {
    const int wave = threadIdx.x >> 6, lane = threadIdx.x & 63;
    const int t = blockIdx.x * 4 + wave;
    const float* xr = x + (size_t)t * DDIM;
    float a0 = 0.f, a1 = 0.f, a2 = 0.f, a3 = 0.f;
    const float4* Wg4 = (const float4*)Wg;  // Wg[d*4 + e] contiguous over e
    for (int d = lane; d < DDIM; d += 64) {
        float xv = xr[d];
        float4 w = Wg4[d];
        a0 += xv * w.x; a1 += xv * w.y; a2 += xv * w.z; a3 += xv * w.w;
    }
#pragma unroll
    for (int off = 32; off; off >>= 1) {
        a0 += __shfl_xor(a0, off); a1 += __shfl_xor(a1, off);
        a2 += __shfl_xor(a2, off); a3 += __shfl_xor(a3, off);
    }
    if (lane == 0) {
        float l[4] = {a0 + bg[0], a1 + bg[1], a2 + bg[2], a3 + bg[3]};
        float mx = fmaxf(fmaxf(l[0], l[1]), fmaxf(l[2], l[3]));
        float p[4], s = 0.f;
#pragma unroll
        for (int e = 0; e < 4; e++) { p[e] = expf(l[e] - mx); s += p[e]; }
#pragma unroll
        for (int e = 0; e < 4; e++) p[e] /= s;
        int e1 = 0;  // argmax, lowest index on ties (strict >)
#pragma unroll
        for (int e = 1; e < 4; e++) if (p[e] > p[e1]) e1 = e;
        int e2 = (e1 == 0) ? 1 : 0;
#pragma unroll
        for (int e = 0; e < 4; e++) if (e != e1 && p[e] > p[e2]) e2 = e;
        const float inv = 1.0f / (p[e1] + p[e2]);
        int pos1 = atomicAdd(&counts[e1], 1);
        perm[e1 * T_TOK + pos1] = t;
        wlist[e1 * T_TOK + pos1] = p[e1] * inv;
        int pos2 = atomicAdd(&counts[e2], 1);
        perm[e2 * T_TOK + pos2] = t;
        wlist[e2 * T_TOK + pos2] = p[e2] * inv;
    }
}

// ===========================================================================
// 256x256 8-phase GEMM, expert-merged:  C = A @ B^T per expert range [e0,e0+nE)
// MODE 0: A rows gathered via perm (tokens); H[hstart+i] = gelu(acc+b1) bf16
// MODE 1: A = H rows (hstart+i); atomicAdd(out[perm[i]], wlist[i]*(acc+b2))
// Block mapping: b -> xcd=b&7 owns bx in {2*xcd, 2*xcd+1}; by sweeps padded
// M-block rows across experts => per-XCD B working set = 2 panels (<=4MB, L2).
// ===========================================================================

#define STAGE_A(t, h, bb)                                                      \
  if ((t) < NT) {                                                              \
    gl_lds16(pa##h##0 + (size_t)(t) * BK, &As[bb][h][w * 512]);                \
    gl_lds16(pa##h##1 + (size_t)(t) * BK, &As[bb][h][w * 512 + 4096]);         \
  }
#define STAGE_B(t, h, bb)                                                      \
  if ((t) < NT) {                                                              \
    gl_lds16(pb##h##0 + (size_t)(t) * BK, &Bs[bb][h][w * 512]);                \
    gl_lds16(pb##h##1 + (size_t)(t) * BK, &Bs[bb][h][w * 512 + 4096]);         \
  }
#define LDA(bb, mg, kk) (*(const bf16x8*)&As[bb][wr][(mg)*1024 + rowOff + offK##kk])
#define LDB(bb, nn, kk) (*(const bf16x8*)&Bs[bb][wch][(nn)*1024 + rowBOff + offK##kk])
#define MFMA4(p, nn)                                                           \
  acc[2*(p)][nn]   = __builtin_amdgcn_mfma_f32_16x16x32_bf16(af0k0, bfr[nn][0], acc[2*(p)][nn], 0, 0, 0);   \
  acc[2*(p)][nn]   = __builtin_amdgcn_mfma_f32_16x16x32_bf16(af0k1, bfr[nn][1], acc[2*(p)][nn], 0, 0, 0);   \
  acc[2*(p)+1][nn] = __builtin_amdgcn_mfma_f32_16x16x32_bf16(af1k0, bfr[nn][0], acc[2*(p)+1][nn], 0, 0, 0); \
  acc[2*(p)+1][nn] = __builtin_amdgcn_mfma_f32_16x16x32_bf16(af1k1, bfr[nn][1], acc[2*(p)+1][nn], 0, 0, 0);
#define PHASE_TAIL(p)                                                          \
  __builtin_amdgcn_s_barrier();                                                \
  asm volatile("s_waitcnt lgkmcnt(0)" ::: "memory");                           \
  __builtin_amdgcn_s_setprio(1);                                               \
  MFMA4(p, 0) MFMA4(p, 1) MFMA4(p, 2) MFMA4(p, 3)                              \
  __builtin_amdgcn_s_setprio(0);                                               \
  __builtin_amdgcn_s_barrier();
// Phase-3 tail: counted vmcnt AFTER the MFMA (max slack), BEFORE the closing
// barrier (closing barrier publishes all waves' gl_lds completions before any
// cross-wave ds_read of the next tile).
#define PHASE_TAIL3(p, t)                                                      \
  __builtin_amdgcn_s_barrier();                                                \
  asm volatile("s_waitcnt lgkmcnt(0)" ::: "memory");                           \
  __builtin_amdgcn_s_setprio(1);                                               \
  MFMA4(p, 0) MFMA4(p, 1) MFMA4(p, 2) MFMA4(p, 3)                              \
  __builtin_amdgcn_s_setprio(0);                                               \
  if ((t) + 2 < NT) { asm volatile("s_waitcnt vmcnt(4)" ::: "memory"); }       \
  else              { asm volatile("s_waitcnt vmcnt(0)" ::: "memory"); }       \
  __builtin_amdgcn_s_barrier();
#define TILE(bb, t)                                                            \
  {                                                                            \
    bfr[0][0] = LDB(bb, 0, 0); bfr[0][1] = LDB(bb, 0, 1);                      \
    bfr[1][0] = LDB(bb, 1, 0); bfr[1][1] = LDB(bb, 1, 1);                      \
    bfr[2][0] = LDB(bb, 2, 0); bfr[2][1] = LDB(bb, 2, 1);                      \
    bfr[3][0] = LDB(bb, 3, 0); bfr[3][1] = LDB(bb, 3, 1);                      \
    af0k0 = LDA(bb, 0, 0); af0k1 = LDA(bb, 0, 1);                              \
    af1k0 = LDA(bb, 1, 0); af1k1 = LDA(bb, 1, 1);                              \
    STAGE_A((t) + 1, 0, (bb) ^ 1)                                              \
    PHASE_TAIL(0)                                                              \
    af0k0 = LDA(bb, 2, 0); af0k1 = LDA(bb, 2, 1);                              \
    af1k0 = LDA(bb, 3, 0); af1k1 = LDA(bb, 3, 1);                              \
    STAGE_A((t) + 1, 1, (bb) ^ 1)                                              \
    PHASE_TAIL(1)                                                              \
    af0k0 = LDA(bb, 4, 0); af0k1 = LDA(bb, 4, 1);                              \
    af1k0 = LDA(bb, 5, 0); af1k1 = LDA(bb, 5, 1);                              \
    STAGE_B((t) + 2, 0, bb)                                                    \
    PHASE_TAIL(2)                                                              \
    af0k0 = LDA(bb, 6, 0); af0k1 = LDA(bb, 6, 1);                              \
    af1k0 = LDA(bb, 7, 0); af1k1 = LDA(bb, 7, 1);                              \
    STAGE_B((t) + 2, 1, bb)                                                    \
    PHASE_TAIL3(3, t)                                                          \
  }

template <int MODE, int KDIM>
__global__ __launch_bounds__(512, 2) void moe_gemm256(
    const __bf16* __restrict__ A, const __bf16* __restrict__ Ball,
    const float* __restrict__ biasAll, __bf16* __restrict__ Hout,
    float* __restrict__ Fout, const int* __restrict__ permAll,
    const float* __restrict__ wlistAll, const int* __restrict__ countsAll,
    int e0, int nE, int HROWS) {
    constexpr int BK = 64;
    constexpr int NT = KDIM / BK;

    __shared__ __align__(16) __bf16 As[2][2][128 * 64];  // [buf][half][row*64+col]
    __shared__ __align__(16) __bf16 Bs[2][2][128 * 64];

    // ---- expert table (uniform, per block) ----
    int cnts[4], cum[5], hs[5];
    cum[0] = 0; hs[0] = 0;
#pragma unroll
    for (int j = 0; j < 4; j++) {
        int c = (j < nE) ? countsAll[e0 + j] : 0;
        cnts[j] = c;
        cum[j + 1] = cum[j] + ((c + 255) >> 8);
        hs[j + 1] = hs[j] + c;
    }
    const int totnb = cum[4];
    const int na = 16 * totnb;
    const int b = blockIdx.x;
    if (b >= na) return;  // block-uniform early exit
    // XCD->bx-pair mapping: xcd = b&7 (HW round-robin), owns 2 N-columns.
    const int xcd = b & 7, loc = b >> 3;
    const int bx = xcd * 2 + (loc & 1);
    const int by = loc >> 1;  // padded M-block row across experts
    int ei = 0;
#pragma unroll
    for (int j = 1; j < 4; j++) if (j < nE && cum[j] <= by) ei = j;
    const int e = e0 + ei;
    const int count = cnts[ei];
    const int m0 = (by - cum[ei]) * 256;  // within-expert padded row base
    const int hstart = hs[ei];            // exact-prefix H row base
    const int n0 = bx * 256;
    const int* __restrict__ perm = permAll + e * T_TOK;
    const float* __restrict__ wlist = (MODE == 1) ? wlistAll + e * T_TOK : nullptr;
    const __bf16* __restrict__ B = Ball + (size_t)e * ODIM * KDIM;
    const float* __restrict__ bias = biasAll + e * ODIM;

    const int tid = threadIdx.x;
    const int w = tid >> 6, lane = tid & 63;
    const int r16 = lane & 15, quad = lane >> 4;
    const int wr = w >> 2;   // 0..1 : M half (128 rows)
    const int wc = w & 3;    // 0..3 : N quarter (64 cols)
    const int wch = wc >> 1; // B half

    // per-lane swizzled LDS read offsets (bf16 elems); row&7 == r16&7 here
    const int swz = r16 & 7;
    const int offK0 = ((quad) ^ swz) * 8;
    const int offK1 = ((quad + 4) ^ swz) * 8;
    const int rowOff = r16 * 64;
    const int rowBOff = (wc & 1) * 4096 + rowOff;

    // staging: thread covers chunk c=tid of each half-tile (row srow, chunk q)
    // pre-swizzled GLOBAL source so linear gl_lds dest yields swizzled LDS
    const int srow = tid >> 3;                    // 0..63
    const int sq = ((tid & 7) ^ (srow & 7)) * 8;  // source col, elems
    const __bf16 *pa00, *pa01, *pa10, *pa11;
    if (MODE == 0) {  // gather token rows (padding rows -> token 0, perm zeroed)
        pa00 = A + (size_t)perm[m0 + srow] * KDIM + sq;
        pa01 = A + (size_t)perm[m0 + 64 + srow] * KDIM + sq;
        pa10 = A + (size_t)perm[m0 + 128 + srow] * KDIM + sq;
        pa11 = A + (size_t)perm[m0 + 192 + srow] * KDIM + sq;
    } else {  // H rows at exact prefix; clamp padded reads inside H
        const int rl = HROWS - 1;
        pa00 = A + (size_t)min(hstart + m0 + srow, rl) * KDIM + sq;
        pa01 = A + (size_t)min(hstart + m0 + 64 + srow, rl) * KDIM + sq;
        pa10 = A + (size_t)min(hstart + m0 + 128 + srow, rl) * KDIM + sq;
        pa11 = A + (size_t)min(hstart + m0 + 192 + srow, rl) * KDIM + sq;
    }
    const __bf16* pb00 = B + (size_t)(n0 + srow) * KDIM + sq;
    const __bf16* pb01 = B + (size_t)(n0 + 64 + srow) * KDIM + sq;
    const __bf16* pb10 = B + (size_t)(n0 + 128 + srow) * KDIM + sq;
    const __bf16* pb11 = B + (size_t)(n0 + 192 + srow) * KDIM + sq;

    f32x4 acc[8][4] = {};
    bf16x8 bfr[4][2];
    bf16x8 af0k0, af0k1, af1k0, af1k1;

    // prologue: B(0), A(0), B(1); counted wait leaves B(1) in flight
    STAGE_B(0, 0, 0) STAGE_B(0, 1, 0)
    STAGE_A(0, 0, 0) STAGE_A(0, 1, 0)
    STAGE_B(1, 0, 1) STAGE_B(1, 1, 1)
    asm volatile("s_waitcnt vmcnt(4)" ::: "memory");
    __builtin_amdgcn_s_barrier();

    for (int t = 0; t < NT; t += 2) {
        TILE(0, t)
        TILE(1, t + 1)
    }

    // Epilogue. D frag layout: row = quad*4 + reg, col = lane&15.
    const int colBase = n0 + wc * 64 + r16;
    const int rowW = m0 + wr * 128 + quad * 4;  // local (within-expert) row
    if (MODE == 0) {
#pragma unroll
        for (int mg = 0; mg < 8; mg++) {
            const int rowBase = rowW + mg * 16;
#pragma unroll
            for (int n = 0; n < 4; n++) {
                const int col = colBase + n * 16;
                const float bv = bias[col];
#pragma unroll
                for (int r = 0; r < 4; r++) {
                    if (rowBase + r < count) {
                        float xv = acc[mg][n][r] + bv;
                        // tanh-form GELU: x * sigmoid(1.59577*x*(1+0.044715*x^2))
                        float u = 1.5957691216057308f * xv * (1.0f + 0.044715f * xv * xv);
                        float gv = xv * __builtin_amdgcn_rcpf(1.0f + __expf(-u));
                        Hout[(size_t)(hstart + rowBase + r) * ODIM + col] = (__bf16)gv;
                    }
                }
            }
        }
    } else {
#pragma unroll
        for (int mg = 0; mg < 8; mg++) {
            const int rowBase = rowW + mg * 16;
            int tok[4]; float g[4]; bool ok[4];
#pragma unroll
            for (int r = 0; r < 4; r++) {
                const int i = rowBase + r;
                ok[r] = (i < count);
                tok[r] = ok[r] ? perm[i] : 0;
                g[r] = ok[r] ? wlist[i] : 0.f;
            }
#pragma unroll
            for (int n = 0; n < 4; n++) {
                const int col = colBase + n * 16;
                const float bv = bias[col];
#pragma unroll
                for (int r = 0; r < 4; r++) {
                    if (ok[r]) {
                        float v = g[r] * (acc[mg][n][r] + bv);
                        atomicAdd(&Fout[(size_t)tok[r] * ODIM + col], v);
                    }
                }
            }
        }
    }
}

#undef STAGE_A
#undef STAGE_B
#undef LDA
#undef LDB
#undef MFMA4
#undef PHASE_TAIL
#undef PHASE_TAIL3
#undef TILE

// ---------------- in-place LayerNorm over last dim (4096) ----------------
__global__ __launch_bounds__(256) void ln_kernel(float* __restrict__ out,
                                                 const float* __restrict__ lw,
                                                 const float* __restrict__ lb,
                                                 const float* __restrict__ gsp) {
    const int t = blockIdx.x;
    float* row = out + (size_t)t * ODIM;
    const float gs = gsp[0];
    float4 v[4];
    float s = 0.f, ss = 0.f;
#pragma unroll
    for (int i = 0; i < 4; i++) {
        float4 a = ((const float4*)row)[threadIdx.x + i * 256];
        a.x *= gs; a.y *= gs; a.z *= gs; a.w *= gs;
        v[i] = a;
        s += a.x + a.y + a.z + a.w;
        ss += a.x * a.x + a.y * a.y + a.z * a.z + a.w * a.w;
    }
#pragma unroll
    for (int off = 32; off; off >>= 1) {
        s += __shfl_xor(s, off);
        ss += __shfl_xor(ss, off);
    }
    __shared__ float rs[4], rss[4];
    const int wave = threadIdx.x >> 6, lane = threadIdx.x & 63;
    if (lane == 0) { rs[wave] = s; rss[wave] = ss; }
    __syncthreads();
    s = rs[0] + rs[1] + rs[2] + rs[3];
    ss = rss[0] + rss[1] + rss[2] + rss[3];
    const float mu = s * (1.0f / ODIM);
    const float var = ss * (1.0f / ODIM) - mu * mu;
    const float inv = 1.0f / sqrtf(var + 1e-5f);
#pragma unroll
    for (int i = 0; i < 4; i++) {
        const int c4 = threadIdx.x + i * 256;
        float4 w4 = ((const float4*)lw)[c4];
        float4 b4 = ((const float4*)lb)[c4];
        float4 o;
        o.x = (v[i].x - mu) * inv * w4.x + b4.x;
        o.y = (v[i].y - mu) * inv * w4.y + b4.y;
        o.z = (v[i].z - mu) * inv * w4.z + b4.z;
        o.w = (v[i].w - mu) * inv * w4.w + b4.w;
        ((float4*)row)[c4] = o;
    }
}

extern "C" void kernel_launch(void* const* d_in, const int* in_sizes, int n_in,
                              void* d_out, int out_size, void* d_ws, size_t ws_size,
                              hipStream_t stream) {
    const float* x   = (const float*)d_in[0];
    const float* Wg  = (const float*)d_in[1];
    const float* bg  = (const float*)d_in[2];
    const float* W1  = (const float*)d_in[3];
    const float* b1  = (const float*)d_in[4];
    const float* W2  = (const float*)d_in[5];
    const float* b2  = (const float*)d_in[6];
    const float* lnw = (const float*)d_in[7];
    const float* lnb = (const float*)d_in[8];
    const float* gsc = (const float*)d_in[9];
    float* out = (float*)d_out;

    const size_t szH2   = (size_t)2 * T_TOK * ODIM * sizeof(__bf16);      // 128 MB (16384 rows)
    const size_t szW2T  = (size_t)NEXP * ODIM * ODIM * sizeof(__bf16);    // 128 MB
    const size_t szXb   = (size_t)T_TOK * DDIM * sizeof(__bf16);          // 16 MB
    const size_t szW1T  = (size_t)NEXP * ODIM * DDIM * sizeof(__bf16);    // 32 MB
    const size_t szH1   = (size_t)T_TOK * ODIM * sizeof(__bf16);          // 64 MB
    const size_t szList = NEXP * sizeof(int) + (size_t)NEXP * T_TOK * 8;
    const size_t needMerged = szH2 + szW2T + szList;  // Xb/W1T aliased into W2T

    char* w = (char*)d_ws;
    const int grid1 = 16 * 67;  // max Sum ceil(count_e/256) = 67 (Sum count = 16384)

    if (ws_size >= needMerged) {
        // ---- merged layout: [H 128MB][W2T 128MB (alias Xb+W1T pre-MODE0)][lists] ----
        __bf16* H   = (__bf16*)w;
        __bf16* W2T = (__bf16*)(w + szH2);
        __bf16* Xb  = W2T;                               // alias (dead after MODE0)
        __bf16* W1T = (__bf16*)((char*)W2T + szXb);      // alias (dead after MODE0)
        int*   counts = (int*)(w + szH2 + szW2T);
        int*   perm   = counts + NEXP;
        float* wlist  = (float*)(perm + NEXP * T_TOK);

        hipMemsetAsync(counts, 0, (NEXP + 2 * NEXP * T_TOK) * sizeof(int), stream);
        hipMemsetAsync(out, 0, (size_t)T_TOK * ODIM * sizeof(float), stream);

        cvt_bf16_vec<<<(T_TOK * DDIM / 4) / 256, 256, 0, stream>>>(x, Xb, T_TOK * DDIM / 4);
        dim3 tb(32, 8);
        transpose_cvt<<<dim3(ODIM / 32, DDIM / 32, NEXP), tb, 0, stream>>>(W1, W1T, DDIM, ODIM);
        router_kernel<<<T_TOK / 4, 256, 0, stream>>>(x, Wg, bg, counts, perm, wlist);

        moe_gemm256<0, DDIM><<<grid1, 512, 0, stream>>>(
            Xb, W1T, b1, H, nullptr, perm, nullptr, counts, 0, NEXP, 2 * T_TOK);
        // W2 transpose AFTER MODE0 (overwrites the Xb/W1T alias region)
        transpose_cvt<<<dim3(ODIM / 32, ODIM / 32, NEXP), tb, 0, stream>>>(W2, W2T, ODIM, ODIM);
        moe_gemm256<1, ODIM><<<grid1, 512, 0, stream>>>(
            H, W2T, b2, nullptr, out, perm, wlist, counts, 0, NEXP, 2 * T_TOK);
    } else {
        // ---- fallback: legacy per-expert layout (~240 MB) ----
        __bf16* Xb  = (__bf16*)w;
        __bf16* W1T = (__bf16*)((char*)Xb + szXb);
        __bf16* W2T = (__bf16*)((char*)W1T + szW1T);
        __bf16* H   = (__bf16*)((char*)W2T + szW2T);
        int*   counts = (int*)((char*)H + szH1);
        int*   perm   = counts + NEXP;
        float* wlist  = (float*)(perm + NEXP * T_TOK);

        hipMemsetAsync(counts, 0, (NEXP + 2 * NEXP * T_TOK) * sizeof(int), stream);
        hipMemsetAsync(out, 0, (size_t)T_TOK * ODIM * sizeof(float), stream);

        cvt_bf16_vec<<<(T_TOK * DDIM / 4) / 256, 256, 0, stream>>>(x, Xb, T_TOK * DDIM / 4);
        dim3 tb(32, 8);
        transpose_cvt<<<dim3(ODIM / 32, DDIM / 32, NEXP), tb, 0, stream>>>(W1, W1T, DDIM, ODIM);
        transpose_cvt<<<dim3(ODIM / 32, ODIM / 32, NEXP), tb, 0, stream>>>(W2, W2T, ODIM, ODIM);
        router_kernel<<<T_TOK / 4, 256, 0, stream>>>(x, Wg, bg, counts, perm, wlist);

        for (int e = 0; e < NEXP; e++) {
            moe_gemm256<0, DDIM><<<16 * 32, 512, 0, stream>>>(
                Xb, W1T, b1, H, nullptr, perm, nullptr, counts, e, 1, T_TOK);
            moe_gemm256<1, ODIM><<<16 * 32, 512, 0, stream>>>(
                H, W2T, b2, nullptr, out, perm, wlist, counts, e, 1, T_TOK);
        }
    }
    ln_kernel<<<T_TOK, 256, 0, stream>>>(out, lnw, lnb, gsc);
}